// Round 1
// baseline (46135.239 us; speedup 1.0000x reference)
//
#include <hip/hip_runtime.h>
#include <math.h>

#define HH    48
#define CFEAT 512
#define HID   256
#define NPOS  (HH*HH)   // 2304
#define TQ    16        // queries per block
#define NEV   64        // evals per block = TQ*4

// ---------------------------------------------------------------------------
// Kernel 1: P[b][pos][n] = b0[n] + sum_c feat[b][c][pos] * W0[c][n]
// 1152 blocks x 256 threads, 4 positions per block.
// ---------------------------------------------------------------------------
__global__ __launch_bounds__(256) void liif_precompute(
    const float* __restrict__ feat, const float* __restrict__ W0,
    const float* __restrict__ b0, float* __restrict__ P)
{
  int blk = blockIdx.x;                 // 0..1151
  int b   = blk / (NPOS/4);             // NPOS/4 = 576
  int p0  = (blk - b*(NPOS/4)) * 4;
  int n   = threadIdx.x;
  const float* f = feat + (size_t)b * CFEAT * NPOS + p0;
  float bias = b0[n];
  float a0 = bias, a1 = bias, a2 = bias, a3 = bias;
  #pragma unroll 4
  for (int c = 0; c < CFEAT; ++c) {
    float w = W0[c*HID + n];
    const float* fr = f + (size_t)c * NPOS;
    a0 += fr[0]*w; a1 += fr[1]*w; a2 += fr[2]*w; a3 += fr[3]*w;
  }
  float* Pp = P + ((size_t)b*NPOS + p0)*HID + n;
  Pp[0*HID] = a0; Pp[1*HID] = a1; Pp[2*HID] = a2; Pp[3*HID] = a3;
}

// ---------------------------------------------------------------------------
// Kernel 2: fused main. Block = 16 queries x 4 shifts = 64 evals, 256 threads.
// ---------------------------------------------------------------------------
__global__ __launch_bounds__(256, 2) void liif_main(
    const float* __restrict__ coord, const float* __restrict__ cell,
    const float* __restrict__ P,  const float* __restrict__ W0,
    const float* __restrict__ W1, const float* __restrict__ b1,
    const float* __restrict__ W2, const float* __restrict__ b2,
    const float* __restrict__ W3, const float* __restrict__ b3,
    const float* __restrict__ W4, const float* __restrict__ b4,
    float* __restrict__ out)
{
  __shared__ __align__(16) float act[NEV][260];   // 260 pad: phase-D bank spread
  __shared__ __align__(16) float wlds[8*HID];     // 8 staged W rows
  __shared__ int   lin_s[NEV];
  __shared__ float r0_s[NEV], r1_s[NEV], rc0_s[NEV], rc1_s[NEV], area_s[NEV];
  __shared__ float pred_s[NEV][3];

  const int t   = threadIdx.x;
  const int blk = blockIdx.x;
  const int b   = blk >> 12;            // 4096 blocks per batch
  const int q0  = (blk & 4095) * TQ;

  // ---- Phase A: indices, rel coords, areas (match numpy fp32 bit-exactly) --
  if (t < NEV) {
    const int e = t;
    const int q = q0 + (e >> 2);
    const int s = e & 3;                // shifts [(-1,-1),(-1,1),(1,-1),(1,1)]
    const size_t cbase = (((size_t)b << 16) + q) * 2;
    float c0 = coord[cbase + 0];
    float c1 = coord[cbase + 1];
    float vx = (s & 2) ? 1.0f : -1.0f;
    float vy = (s & 1) ? 1.0f : -1.0f;
    const float RXY = (float)(1.0/48.0);
    const float CLO = (float)(-1.0 + 1e-6);
    const float CHI = (float)( 1.0 - 1e-6);
    float gx = __fadd_rn(c0, __fadd_rn(__fmul_rn(vx, RXY), 1e-6f));
    float gy = __fadd_rn(c1, __fadd_rn(__fmul_rn(vy, RXY), 1e-6f));
    gx = fminf(fmaxf(gx, CLO), CHI);
    gy = fminf(fmaxf(gy, CLO), CHI);
    // x = ((g+1)*48 - 1) / 2, round half-to-even, clip
    float xr = __fmul_rn(__fsub_rn(__fmul_rn(__fadd_rn(gx, 1.0f), 48.0f), 1.0f), 0.5f);
    float xc = __fmul_rn(__fsub_rn(__fmul_rn(__fadd_rn(gy, 1.0f), 48.0f), 1.0f), 0.5f);
    int ir = (int)rintf(xr); ir = ir < 0 ? 0 : (ir > HH-1 ? HH-1 : ir);
    int ic = (int)rintf(xc); ic = ic < 0 ? 0 : (ic > HH-1 ? HH-1 : ic);
    lin_s[e] = ir*HH + ic;
    const float T2 = (float)(2.0/48.0);
    float qcr = __fsub_rn(__fmul_rn(__fadd_rn((float)ir, 0.5f), T2), 1.0f);
    float qcc = __fsub_rn(__fmul_rn(__fadd_rn((float)ic, 0.5f), T2), 1.0f);
    float r0 = __fmul_rn(__fsub_rn(c0, qcr), 48.0f);
    float r1 = __fmul_rn(__fsub_rn(c1, qcc), 48.0f);
    r0_s[e] = r0; r1_s[e] = r1;
    area_s[e] = __fadd_rn(fabsf(__fmul_rn(r0, r1)), 1e-9f);
    rc0_s[e] = __fmul_rn(cell[cbase + 0], 48.0f);
    rc1_s[e] = __fmul_rn(cell[cbase + 1], 48.0f);
  }
  __syncthreads();

  // ---- Phase B: h0[e][n] = relu(P[b][lin][n] + rel/cell terms) -------------
  {
    float w512 = W0[(size_t)512*HID + t];
    float w513 = W0[(size_t)513*HID + t];
    float w514 = W0[(size_t)514*HID + t];
    float w515 = W0[(size_t)515*HID + t];
    const float* Pb = P + (size_t)b * NPOS * HID;
    #pragma unroll 4
    for (int e = 0; e < NEV; ++e) {
      float v = Pb[(size_t)lin_s[e]*HID + t];
      v += r0_s[e]*w512 + r1_s[e]*w513 + rc0_s[e]*w514 + rc1_s[e]*w515;
      act[e][t] = fmaxf(v, 0.0f);
    }
  }
  // (no sync needed here: first kc-loop __syncthreads covers it)

  // ---- Layers 1..3: act = relu(act @ W + b), 8x8 register micro-tile -------
  const int ty = t >> 5;                // 8 eval-groups of 8
  const int tx = t & 31;                // 32 output-groups of 8
  const float* const Wl[3] = {W1, W2, W3};
  const float* const bl[3] = {b1, b2, b3};

  #pragma unroll
  for (int L = 0; L < 3; ++L) {
    const float* __restrict__ W = Wl[L];
    float4 bv0 = *(const float4*)&bl[L][8*tx];
    float4 bv1 = *(const float4*)&bl[L][8*tx + 4];
    float4 acc0[8], acc1[8];
    #pragma unroll
    for (int i = 0; i < 8; ++i) { acc0[i] = bv0; acc1[i] = bv1; }

    for (int kc = 0; kc < HID; kc += 8) {
      __syncthreads();                                  // wlds readers done
      *(float4*)&wlds[t*8]     = *(const float4*)&W[(size_t)kc*HID + t*8];
      *(float4*)&wlds[t*8 + 4] = *(const float4*)&W[(size_t)kc*HID + t*8 + 4];
      __syncthreads();
      #pragma unroll
      for (int g = 0; g < 2; ++g) {
        float4 a4[8];
        #pragma unroll
        for (int i = 0; i < 8; ++i)
          a4[i] = *(const float4*)&act[8*ty + i][kc + 4*g];
        #pragma unroll
        for (int kk = 0; kk < 4; ++kk) {
          float4 w0 = *(const float4*)&wlds[(4*g + kk)*HID + 8*tx];
          float4 w1 = *(const float4*)&wlds[(4*g + kk)*HID + 8*tx + 4];
          #pragma unroll
          for (int i = 0; i < 8; ++i) {
            float a = (kk==0) ? a4[i].x : (kk==1) ? a4[i].y : (kk==2) ? a4[i].z : a4[i].w;
            acc0[i].x += a*w0.x; acc0[i].y += a*w0.y; acc0[i].z += a*w0.z; acc0[i].w += a*w0.w;
            acc1[i].x += a*w1.x; acc1[i].y += a*w1.y; acc1[i].z += a*w1.z; acc1[i].w += a*w1.w;
          }
        }
      }
    }
    __syncthreads();                                    // all act reads done
    #pragma unroll
    for (int i = 0; i < 8; ++i) {
      float4 v0 = acc0[i], v1 = acc1[i];
      v0.x = fmaxf(v0.x, 0.f); v0.y = fmaxf(v0.y, 0.f);
      v0.z = fmaxf(v0.z, 0.f); v0.w = fmaxf(v0.w, 0.f);
      v1.x = fmaxf(v1.x, 0.f); v1.y = fmaxf(v1.y, 0.f);
      v1.z = fmaxf(v1.z, 0.f); v1.w = fmaxf(v1.w, 0.f);
      *(float4*)&act[8*ty + i][8*tx]     = v0;
      *(float4*)&act[8*ty + i][8*tx + 4] = v1;
    }
  }
  __syncthreads();

  // ---- Phase D: final 256->3 layer + area-weighted blend -------------------
  if (t < NEV*3) {
    int e = t / 3, o = t - (t/3)*3;
    float accd = b4[o];
    #pragma unroll 8
    for (int k = 0; k < HID; ++k) accd += act[e][k] * W4[k*3 + o];
    pred_s[e][o] = accd;
  }
  __syncthreads();
  if (t < TQ*3) {
    int q = t / 3, o = t - (t/3)*3;
    int eb = q*4;
    float a0 = area_s[eb+0], a1 = area_s[eb+1], a2 = area_s[eb+2], a3 = area_s[eb+3];
    float tot = ((a0 + a1) + a2) + a3;
    // weights reversed: w[s] = area[3-s]/tot
    float rv = (pred_s[eb+0][o]*a3 + pred_s[eb+1][o]*a2 +
                pred_s[eb+2][o]*a1 + pred_s[eb+3][o]*a0) / tot;
    out[(((size_t)b << 16) + (q0 + q))*3 + o] = rv;
  }
}

// ---------------------------------------------------------------------------
extern "C" void kernel_launch(void* const* d_in, const int* in_sizes, int n_in,
                              void* d_out, int out_size, void* d_ws, size_t ws_size,
                              hipStream_t stream)
{
  const float* feat  = (const float*)d_in[0];
  const float* coord = (const float*)d_in[1];
  const float* cell  = (const float*)d_in[2];
  const float* W0    = (const float*)d_in[3];
  const float* b0    = (const float*)d_in[4];
  const float* W1    = (const float*)d_in[5];
  const float* b1    = (const float*)d_in[6];
  const float* W2    = (const float*)d_in[7];
  const float* b2    = (const float*)d_in[8];
  const float* W3    = (const float*)d_in[9];
  const float* b3    = (const float*)d_in[10];
  const float* W4    = (const float*)d_in[11];
  const float* b4    = (const float*)d_in[12];
  float* outp = (float*)d_out;
  float* P    = (float*)d_ws;   // 2*2304*256 f32 = 4.72 MB scratch

  hipLaunchKernelGGL(liif_precompute, dim3(2*(NPOS/4)), dim3(256), 0, stream,
                     feat, W0, b0, P);
  hipLaunchKernelGGL(liif_main, dim3(8192), dim3(256), 0, stream,
                     coord, cell, P, W0, W1, b1, W2, b2, W3, b3, W4, b4, outp);
}

// Round 2
// 571.894 us; speedup vs baseline: 80.6709x; 80.6709x over previous
//
#include <hip/hip_runtime.h>
#include <math.h>

#define HH    48
#define CFEAT 512
#define HID   256
#define NPOS  (HH*HH)   // 2304
#define TQ    16        // queries per block
#define NEV   64        // evals per block = TQ*4
#define ACTP  264       // padded act row (bf16 elems): 528B stride -> 2-way banks
#define WROW  40        // padded wbuf row (bf16 elems): 80B stride -> 2-way banks

typedef __attribute__((ext_vector_type(8))) short bf16x8;
typedef __attribute__((ext_vector_type(4))) float f32x4;

static __device__ __forceinline__ unsigned short f2bf(float x) {
  unsigned int u = __float_as_uint(x);
  u += 0x7fffu + ((u >> 16) & 1u);     // RNE
  return (unsigned short)(u >> 16);
}
static __device__ __forceinline__ float bf2f(unsigned short h) {
  return __uint_as_float(((unsigned int)h) << 16);
}

// ---------------------------------------------------------------------------
// Kernel 1: P[b][pos][n] = b0[n] + sum_c feat[b][c][pos] * W0[c][n]  (fp32)
// ---------------------------------------------------------------------------
__global__ __launch_bounds__(256) void liif_precompute(
    const float* __restrict__ feat, const float* __restrict__ W0,
    const float* __restrict__ b0, float* __restrict__ P)
{
  int blk = blockIdx.x;                 // 0..1151
  int b   = blk / (NPOS/4);
  int p0  = (blk - b*(NPOS/4)) * 4;
  int n   = threadIdx.x;
  const float* f = feat + (size_t)b * CFEAT * NPOS + p0;
  float bias = b0[n];
  float a0 = bias, a1 = bias, a2 = bias, a3 = bias;
  #pragma unroll 4
  for (int c = 0; c < CFEAT; ++c) {
    float w = W0[c*HID + n];
    const float* fr = f + (size_t)c * NPOS;
    a0 += fr[0]*w; a1 += fr[1]*w; a2 += fr[2]*w; a3 += fr[3]*w;
  }
  float* Pp = P + ((size_t)b*NPOS + p0)*HID + n;
  Pp[0*HID] = a0; Pp[1*HID] = a1; Pp[2*HID] = a2; Pp[3*HID] = a3;
}

// ---------------------------------------------------------------------------
// Kernel 2: transpose+convert W1..W3 -> bf16 Wt[l][n][k]; W4 -> f32 W4t[o][k]
// ---------------------------------------------------------------------------
__global__ __launch_bounds__(256) void liif_convert(
    const float* __restrict__ W1, const float* __restrict__ W2,
    const float* __restrict__ W3, const float* __restrict__ W4,
    unsigned short* __restrict__ wt, float* __restrict__ w4t)
{
  int b = blockIdx.x, t = threadIdx.x;
  if (b < 768) {
    int l = b >> 8, n = b & 255;
    const float* W = (l == 0) ? W1 : (l == 1) ? W2 : W3;
    wt[l*65536 + n*256 + t] = f2bf(W[t*256 + n]);   // Wt[n][k] = W[k][n]
  } else {
    for (int o = 0; o < 3; ++o) w4t[o*256 + t] = W4[t*3 + o];
  }
}

// ---------------------------------------------------------------------------
// Kernel 3: fused main. 64 evals/block, 4 waves; MFMA bf16 layers 1..3.
// ---------------------------------------------------------------------------
__global__ __launch_bounds__(256) void liif_main(
    const float* __restrict__ coord, const float* __restrict__ cell,
    const float* __restrict__ P,  const float* __restrict__ W0,
    const unsigned short* __restrict__ wt,
    const float* __restrict__ b1, const float* __restrict__ b2,
    const float* __restrict__ b3, const float* __restrict__ b4,
    const float* __restrict__ w4t, float* __restrict__ out)
{
  __shared__ __align__(16) unsigned short act[NEV*ACTP];   // 33.8 KB
  __shared__ __align__(16) unsigned short wbuf[256*WROW];  // 20 KB
  __shared__ int   lin_s[NEV];
  __shared__ float r0_s[NEV], r1_s[NEV], rc0_s[NEV], rc1_s[NEV], area_s[NEV];
  __shared__ float pred_s[NEV][3];

  const int t   = threadIdx.x;
  const int blk = blockIdx.x;
  const int b   = blk >> 12;            // 4096 blocks per batch
  const int q0  = (blk & 4095) * TQ;

  // ---- Phase A: indices, rel coords, areas (bit-exact vs numpy fp32) ------
  if (t < NEV) {
    const int e = t;
    const int q = q0 + (e >> 2);
    const int s = e & 3;                // [(-1,-1),(-1,1),(1,-1),(1,1)]
    const size_t cbase = (((size_t)b << 16) + q) * 2;
    float c0 = coord[cbase + 0];
    float c1 = coord[cbase + 1];
    float vx = (s & 2) ? 1.0f : -1.0f;
    float vy = (s & 1) ? 1.0f : -1.0f;
    const float RXY = (float)(1.0/48.0);
    const float CLO = (float)(-1.0 + 1e-6);
    const float CHI = (float)( 1.0 - 1e-6);
    float gx = __fadd_rn(c0, __fadd_rn(__fmul_rn(vx, RXY), 1e-6f));
    float gy = __fadd_rn(c1, __fadd_rn(__fmul_rn(vy, RXY), 1e-6f));
    gx = fminf(fmaxf(gx, CLO), CHI);
    gy = fminf(fmaxf(gy, CLO), CHI);
    float xr = __fmul_rn(__fsub_rn(__fmul_rn(__fadd_rn(gx, 1.0f), 48.0f), 1.0f), 0.5f);
    float xc = __fmul_rn(__fsub_rn(__fmul_rn(__fadd_rn(gy, 1.0f), 48.0f), 1.0f), 0.5f);
    int ir = (int)rintf(xr); ir = ir < 0 ? 0 : (ir > HH-1 ? HH-1 : ir);
    int ic = (int)rintf(xc); ic = ic < 0 ? 0 : (ic > HH-1 ? HH-1 : ic);
    lin_s[e] = ir*HH + ic;
    const float T2 = (float)(2.0/48.0);
    float qcr = __fsub_rn(__fmul_rn(__fadd_rn((float)ir, 0.5f), T2), 1.0f);
    float qcc = __fsub_rn(__fmul_rn(__fadd_rn((float)ic, 0.5f), T2), 1.0f);
    float r0 = __fmul_rn(__fsub_rn(c0, qcr), 48.0f);
    float r1 = __fmul_rn(__fsub_rn(c1, qcc), 48.0f);
    r0_s[e] = r0; r1_s[e] = r1;
    area_s[e] = __fadd_rn(fabsf(__fmul_rn(r0, r1)), 1e-9f);
    rc0_s[e] = __fmul_rn(cell[cbase + 0], 48.0f);
    rc1_s[e] = __fmul_rn(cell[cbase + 1], 48.0f);
  }
  __syncthreads();

  // ---- Phase B: h0[e][t] = relu(P[lin][t] + rel terms) -> bf16 LDS --------
  {
    float w512 = W0[(size_t)512*HID + t];
    float w513 = W0[(size_t)513*HID + t];
    float w514 = W0[(size_t)514*HID + t];
    float w515 = W0[(size_t)515*HID + t];
    const float* Pb = P + (size_t)b * NPOS * HID;
    #pragma unroll 4
    for (int e = 0; e < NEV; ++e) {
      float v = Pb[(size_t)lin_s[e]*HID + t];
      v += r0_s[e]*w512 + r1_s[e]*w513 + rc0_s[e]*w514 + rc1_s[e]*w515;
      act[e*ACTP + t] = f2bf(fmaxf(v, 0.0f));
    }
  }
  // (first kc-loop barrier covers Phase B completion)

  // ---- Layers 1..3: MFMA 16x16x32 bf16; each wave owns 16 eval-rows -------
  const int lane = t & 63;
  const int m0   = (t >> 6) * 16;       // wave's row base
  const int lr   = lane & 15;           // row-in-tile (A) / col-in-tile (B,D)
  const int lk   = lane >> 4;           // k-group (x8)

  #pragma unroll 1
  for (int l = 0; l < 3; ++l) {
    const unsigned short* Wt = wt + l*65536;       // Wt[n][k] bf16
    const float* bl = (l == 0) ? b1 : (l == 1) ? b2 : b3;
    f32x4 acc[16];
    #pragma unroll
    for (int nt = 0; nt < 16; ++nt) acc[nt] = (f32x4){0.f, 0.f, 0.f, 0.f};

    for (int kc = 0; kc < 8; ++kc) {               // K chunks of 32
      __syncthreads();                             // prev chunk fully consumed
      // stage Wt[0..255][kc*32..+31] -> wbuf (coalesced 64B per row)
      {
        const int ks = (t & 3) * 8;
        const int nb = t >> 2;
        #pragma unroll
        for (int s = 0; s < 4; ++s) {
          const int n = nb + 64*s;
          *(f32x4*)&wbuf[n*WROW + ks] =
              *(const f32x4*)&Wt[n*256 + kc*32 + ks];
        }
      }
      __syncthreads();                             // chunk ready
      bf16x8 af = *(const bf16x8*)&act[(m0 + lr)*ACTP + kc*32 + lk*8];
      #pragma unroll
      for (int nt = 0; nt < 16; ++nt) {
        bf16x8 bv = *(const bf16x8*)&wbuf[(nt*16 + lr)*WROW + lk*8];
        acc[nt] = __builtin_amdgcn_mfma_f32_16x16x32_bf16(af, bv, acc[nt], 0, 0, 0);
      }
    }
    // writeback: bias + relu -> bf16 act (wave-private rows, no barrier)
    #pragma unroll
    for (int nt = 0; nt < 16; ++nt) {
      float bv = bl[nt*16 + lr];
      #pragma unroll
      for (int j = 0; j < 4; ++j) {
        float v = fmaxf(acc[nt][j] + bv, 0.0f);
        act[(m0 + lk*4 + j)*ACTP + nt*16 + lr] = f2bf(v);
      }
    }
  }
  __syncthreads();

  // ---- Phase D: final 256->3 layer ---------------------------------------
  if (t < NEV*3) {
    const int e = t / 3, o = t - (t/3)*3;
    const float* w4o = w4t + o*256;
    float a = b4[o];
    #pragma unroll 4
    for (int k = 0; k < HID; k += 8) {
      bf16x8 av = *(const bf16x8*)&act[e*ACTP + k];
      f32x4 wa = *(const f32x4*)&w4o[k];
      f32x4 wb = *(const f32x4*)&w4o[k+4];
      a += bf2f((unsigned short)av[0])*wa[0] + bf2f((unsigned short)av[1])*wa[1]
         + bf2f((unsigned short)av[2])*wa[2] + bf2f((unsigned short)av[3])*wa[3]
         + bf2f((unsigned short)av[4])*wb[0] + bf2f((unsigned short)av[5])*wb[1]
         + bf2f((unsigned short)av[6])*wb[2] + bf2f((unsigned short)av[7])*wb[3];
    }
    pred_s[e][o] = a;
  }
  __syncthreads();

  // ---- blend: w[s] = area[3-s]/tot ---------------------------------------
  if (t < TQ*3) {
    const int q = t / 3, o = t - (t/3)*3;
    const int eb = q*4;
    float a0 = area_s[eb+0], a1 = area_s[eb+1], a2 = area_s[eb+2], a3 = area_s[eb+3];
    float tot = ((a0 + a1) + a2) + a3;
    float rv = (pred_s[eb+0][o]*a3 + pred_s[eb+1][o]*a2 +
                pred_s[eb+2][o]*a1 + pred_s[eb+3][o]*a0) / tot;
    out[(((size_t)b << 16) + (q0 + q))*3 + o] = rv;
  }
}

// ---------------------------------------------------------------------------
extern "C" void kernel_launch(void* const* d_in, const int* in_sizes, int n_in,
                              void* d_out, int out_size, void* d_ws, size_t ws_size,
                              hipStream_t stream)
{
  const float* feat  = (const float*)d_in[0];
  const float* coord = (const float*)d_in[1];
  const float* cell  = (const float*)d_in[2];
  const float* W0    = (const float*)d_in[3];
  const float* b0    = (const float*)d_in[4];
  const float* W1    = (const float*)d_in[5];
  const float* b1    = (const float*)d_in[6];
  const float* W2    = (const float*)d_in[7];
  const float* b2    = (const float*)d_in[8];
  const float* W3    = (const float*)d_in[9];
  const float* b3    = (const float*)d_in[10];
  const float* W4    = (const float*)d_in[11];
  const float* b4    = (const float*)d_in[12];
  float* outp = (float*)d_out;

  // ws layout: P f32 [2*2304*256] = 4,718,592 B | Wt bf16 3*64K = 393,216 B
  //            | W4t f32 3*256 = 3,072 B  (total ~4.88 MB)
  float*          P    = (float*)d_ws;
  unsigned short* wtp  = (unsigned short*)((char*)d_ws + 4718592);
  float*          w4tp = (float*)((char*)d_ws + 4718592 + 393216);

  hipLaunchKernelGGL(liif_precompute, dim3(2*(NPOS/4)), dim3(256), 0, stream,
                     feat, W0, b0, P);
  hipLaunchKernelGGL(liif_convert, dim3(769), dim3(256), 0, stream,
                     W1, W2, W3, W4, wtp, w4tp);
  hipLaunchKernelGGL(liif_main, dim3(8192), dim3(256), 0, stream,
                     coord, cell, P, W0, wtp, b1, b2, b3, b4, w4tp, outp);
}

// Round 3
// 456.901 us; speedup vs baseline: 100.9743x; 1.2517x over previous
//
#include <hip/hip_runtime.h>
#include <math.h>

#define HH    48
#define CFEAT 512
#define HID   256
#define NPOS  (HH*HH)   // 2304
#define TQ    32        // queries per block
#define NEV   128       // evals per block = TQ*4
#define ACTP  264       // padded act row (bf16): 528B stride -> 2-way-free banks
#define WROW  40        // padded wbuf row (bf16): 80B stride -> 2-way-free banks

typedef __attribute__((ext_vector_type(8))) short bf16x8;
typedef __attribute__((ext_vector_type(4))) float f32x4;

static __device__ __forceinline__ unsigned short f2bf(float x) {
  unsigned int u = __float_as_uint(x);
  u += 0x7fffu + ((u >> 16) & 1u);     // RNE
  return (unsigned short)(u >> 16);
}
static __device__ __forceinline__ float bf2f(unsigned short h) {
  return __uint_as_float(((unsigned int)h) << 16);
}

// ---------------------------------------------------------------------------
// Kernel 1: P[b][pos][n] = b0[n] + sum_c feat[b][c][pos] * W0[c][n]  (fp32)
// ---------------------------------------------------------------------------
__global__ __launch_bounds__(256) void liif_precompute(
    const float* __restrict__ feat, const float* __restrict__ W0,
    const float* __restrict__ b0, float* __restrict__ P)
{
  int blk = blockIdx.x;                 // 0..1151
  int b   = blk / (NPOS/4);
  int p0  = (blk - b*(NPOS/4)) * 4;
  int n   = threadIdx.x;
  const float* f = feat + (size_t)b * CFEAT * NPOS + p0;
  float bias = b0[n];
  float a0 = bias, a1 = bias, a2 = bias, a3 = bias;
  #pragma unroll 4
  for (int c = 0; c < CFEAT; ++c) {
    float w = W0[c*HID + n];
    const float* fr = f + (size_t)c * NPOS;
    a0 += fr[0]*w; a1 += fr[1]*w; a2 += fr[2]*w; a3 += fr[3]*w;
  }
  float* Pp = P + ((size_t)b*NPOS + p0)*HID + n;
  Pp[0*HID] = a0; Pp[1*HID] = a1; Pp[2*HID] = a2; Pp[3*HID] = a3;
}

// ---------------------------------------------------------------------------
// Kernel 2: transpose+convert W1..W3 -> bf16 Wt[l][n][k]; W4 -> f32 W4t[o][k]
// ---------------------------------------------------------------------------
__global__ __launch_bounds__(256) void liif_convert(
    const float* __restrict__ W1, const float* __restrict__ W2,
    const float* __restrict__ W3, const float* __restrict__ W4,
    unsigned short* __restrict__ wt, float* __restrict__ w4t)
{
  int b = blockIdx.x, t = threadIdx.x;
  if (b < 768) {
    int l = b >> 8, n = b & 255;
    const float* W = (l == 0) ? W1 : (l == 1) ? W2 : W3;
    wt[l*65536 + n*256 + t] = f2bf(W[t*256 + n]);   // Wt[n][k] = W[k][n]
  } else {
    for (int o = 0; o < 3; ++o) w4t[o*256 + t] = W4[t*3 + o];
  }
}

// ---------------------------------------------------------------------------
// Kernel 3: fused main. 128 evals/block, 8 waves; wave = 64x64 output tile.
// ---------------------------------------------------------------------------
__global__ __launch_bounds__(512, 2) void liif_main(
    const float* __restrict__ coord, const float* __restrict__ cell,
    const float* __restrict__ P,  const float* __restrict__ W0,
    const unsigned short* __restrict__ wt,
    const float* __restrict__ b1, const float* __restrict__ b2,
    const float* __restrict__ b3, const float* __restrict__ b4,
    const float* __restrict__ w4t, float* __restrict__ out)
{
  __shared__ __align__(16) unsigned short act[NEV*ACTP];      // 67.6 KB
  __shared__ __align__(16) unsigned short wbuf[2][256*WROW];  // 41 KB
  __shared__ int   lin_s[NEV];
  __shared__ float r0_s[NEV], r1_s[NEV], rc0_s[NEV], rc1_s[NEV], area_s[NEV];
  __shared__ float pred_s[NEV][3];

  const int t   = threadIdx.x;
  const int blk = blockIdx.x;
  const int b   = blk >> 11;            // 2048 blocks per batch
  const int q0  = (blk & 2047) * TQ;

  // ---- Phase A: indices, rel coords, areas (bit-exact vs numpy fp32) ------
  if (t < NEV) {
    const int e = t;
    const int q = q0 + (e >> 2);
    const int s = e & 3;                // [(-1,-1),(-1,1),(1,-1),(1,1)]
    const size_t cbase = (((size_t)b << 16) + q) * 2;
    float c0 = coord[cbase + 0];
    float c1 = coord[cbase + 1];
    float vx = (s & 2) ? 1.0f : -1.0f;
    float vy = (s & 1) ? 1.0f : -1.0f;
    const float RXY = (float)(1.0/48.0);
    const float CLO = (float)(-1.0 + 1e-6);
    const float CHI = (float)( 1.0 - 1e-6);
    float gx = __fadd_rn(c0, __fadd_rn(__fmul_rn(vx, RXY), 1e-6f));
    float gy = __fadd_rn(c1, __fadd_rn(__fmul_rn(vy, RXY), 1e-6f));
    gx = fminf(fmaxf(gx, CLO), CHI);
    gy = fminf(fmaxf(gy, CLO), CHI);
    float xr = __fmul_rn(__fsub_rn(__fmul_rn(__fadd_rn(gx, 1.0f), 48.0f), 1.0f), 0.5f);
    float xc = __fmul_rn(__fsub_rn(__fmul_rn(__fadd_rn(gy, 1.0f), 48.0f), 1.0f), 0.5f);
    int ir = (int)rintf(xr); ir = ir < 0 ? 0 : (ir > HH-1 ? HH-1 : ir);
    int ic = (int)rintf(xc); ic = ic < 0 ? 0 : (ic > HH-1 ? HH-1 : ic);
    lin_s[e] = ir*HH + ic;
    const float T2 = (float)(2.0/48.0);
    float qcr = __fsub_rn(__fmul_rn(__fadd_rn((float)ir, 0.5f), T2), 1.0f);
    float qcc = __fsub_rn(__fmul_rn(__fadd_rn((float)ic, 0.5f), T2), 1.0f);
    float r0 = __fmul_rn(__fsub_rn(c0, qcr), 48.0f);
    float r1 = __fmul_rn(__fsub_rn(c1, qcc), 48.0f);
    r0_s[e] = r0; r1_s[e] = r1;
    area_s[e] = __fadd_rn(fabsf(__fmul_rn(r0, r1)), 1e-9f);
    rc0_s[e] = __fmul_rn(cell[cbase + 0], 48.0f);
    rc1_s[e] = __fmul_rn(cell[cbase + 1], 48.0f);
  }
  __syncthreads();

  // ---- Phase B: h0 -> bf16 act. 512 thr: 128 cols-pairs x 4 row-quarters --
  {
    const int c2 = (t & 127) * 2;       // column pair
    const int rq = t >> 7;              // row quarter
    float wA = W0[(size_t)512*HID + c2],  wB = W0[(size_t)512*HID + c2 + 1];
    float xA = W0[(size_t)513*HID + c2],  xB = W0[(size_t)513*HID + c2 + 1];
    float yA = W0[(size_t)514*HID + c2],  yB = W0[(size_t)514*HID + c2 + 1];
    float zA = W0[(size_t)515*HID + c2],  zB = W0[(size_t)515*HID + c2 + 1];
    const float* Pb = P + (size_t)b * NPOS * HID;
    #pragma unroll 4
    for (int i = 0; i < 32; ++i) {
      const int e = rq*32 + i;
      const float* pr = Pb + (size_t)lin_s[e]*HID + c2;
      float vA = pr[0] + r0_s[e]*wA + r1_s[e]*xA + rc0_s[e]*yA + rc1_s[e]*zA;
      float vB = pr[1] + r0_s[e]*wB + r1_s[e]*xB + rc0_s[e]*yB + rc1_s[e]*zB;
      unsigned int pk = (unsigned int)f2bf(fmaxf(vA, 0.0f)) |
                        ((unsigned int)f2bf(fmaxf(vB, 0.0f)) << 16);
      *(unsigned int*)&act[e*ACTP + c2] = pk;
    }
  }
  // (stage-0 barrier of layer 0 covers Phase B completion)

  // ---- Layers 1..3: MFMA 16x16x32; wave tile 64x64; dbuf wbuf, T14 stage --
  const int lane = t & 63;
  const int w    = t >> 6;              // 0..7
  const int m0   = (w >> 2) * 64;       // row base (0 / 64)
  const int n0   = (w & 3) * 64;        // col base (0/64/128/192)
  const int lr   = lane & 15;
  const int lk   = lane >> 4;
  const int sn   = t >> 2;              // staging row 0..127
  const int sp   = (t & 3) * 8;         // staging k-offset

  #pragma unroll 1
  for (int l = 0; l < 3; ++l) {
    const unsigned short* Wt = wt + l*65536;       // Wt[n][k] bf16
    const float* bl = (l == 0) ? b1 : (l == 1) ? b2 : b3;

    // stage chunk 0 -> wbuf[0]
    {
      f32x4 s0 = *(const f32x4*)&Wt[(size_t)sn*256 + sp];
      f32x4 s1 = *(const f32x4*)&Wt[(size_t)(sn+128)*256 + sp];
      *(f32x4*)&wbuf[0][sn*WROW + sp]       = s0;
      *(f32x4*)&wbuf[0][(sn+128)*WROW + sp] = s1;
    }
    __syncthreads();

    f32x4 acc[16];
    #pragma unroll
    for (int i = 0; i < 16; ++i) acc[i] = (f32x4){0.f, 0.f, 0.f, 0.f};

    #pragma unroll 1
    for (int kc = 0; kc < 8; ++kc) {
      const unsigned short* wb = wbuf[kc & 1];
      f32x4 s0, s1;
      if (kc < 7) {                                // prefetch next chunk
        s0 = *(const f32x4*)&Wt[(size_t)sn*256 + (kc+1)*32 + sp];
        s1 = *(const f32x4*)&Wt[(size_t)(sn+128)*256 + (kc+1)*32 + sp];
      }
      bf16x8 af[4], bf[4];
      #pragma unroll
      for (int mt = 0; mt < 4; ++mt)
        af[mt] = *(const bf16x8*)&act[(m0 + mt*16 + lr)*ACTP + kc*32 + lk*8];
      #pragma unroll
      for (int nt = 0; nt < 4; ++nt)
        bf[nt] = *(const bf16x8*)&wb[(n0 + nt*16 + lr)*WROW + lk*8];
      #pragma unroll
      for (int mt = 0; mt < 4; ++mt)
        #pragma unroll
        for (int nt = 0; nt < 4; ++nt)
          acc[mt*4 + nt] = __builtin_amdgcn_mfma_f32_16x16x32_bf16(
              af[mt], bf[nt], acc[mt*4 + nt], 0, 0, 0);
      if (kc < 7) {
        unsigned short* wn = wbuf[(kc + 1) & 1];
        *(f32x4*)&wn[sn*WROW + sp]       = s0;
        *(f32x4*)&wn[(sn+128)*WROW + sp] = s1;
      }
      __syncthreads();                             // one barrier per chunk
    }

    // writeback: bias + relu -> bf16 act (rows owned by (w>>2), cols by w&3;
    // barrier at end of chunk 7 ensured all act reads of this layer done)
    #pragma unroll
    for (int nt = 0; nt < 4; ++nt) {
      float bv = bl[n0 + nt*16 + lr];
      #pragma unroll
      for (int mt = 0; mt < 4; ++mt) {
        #pragma unroll
        for (int j = 0; j < 4; ++j) {
          float v = fmaxf(acc[mt*4 + nt][j] + bv, 0.0f);
          act[(m0 + mt*16 + lk*4 + j)*ACTP + n0 + nt*16 + lr] = f2bf(v);
        }
      }
    }
    // next layer's stage0 + barrier orders writeback before next reads
  }
  __syncthreads();

  // ---- Phase D: final 256->3 layer (each act row read once) ---------------
  if (t < NEV) {
    const int e = t;
    float a0 = b4[0], a1 = b4[1], a2 = b4[2];
    #pragma unroll 4
    for (int k = 0; k < HID; k += 8) {
      bf16x8 av = *(const bf16x8*)&act[e*ACTP + k];
      #pragma unroll
      for (int i = 0; i < 8; ++i) {
        float v = bf2f((unsigned short)av[i]);
        a0 += v * w4t[k + i];
        a1 += v * w4t[256 + k + i];
        a2 += v * w4t[512 + k + i];
      }
    }
    pred_s[e][0] = a0; pred_s[e][1] = a1; pred_s[e][2] = a2;
  }
  __syncthreads();

  // ---- blend: w[s] = area[3-s]/tot ---------------------------------------
  if (t < TQ*3) {
    const int q = t / 3, o = t - (t/3)*3;
    const int eb = q*4;
    float a0 = area_s[eb+0], a1 = area_s[eb+1], a2 = area_s[eb+2], a3 = area_s[eb+3];
    float tot = ((a0 + a1) + a2) + a3;
    float rv = (pred_s[eb+0][o]*a3 + pred_s[eb+1][o]*a2 +
                pred_s[eb+2][o]*a1 + pred_s[eb+3][o]*a0) / tot;
    out[(((size_t)b << 16) + (q0 + q))*3 + o] = rv;
  }
}

// ---------------------------------------------------------------------------
extern "C" void kernel_launch(void* const* d_in, const int* in_sizes, int n_in,
                              void* d_out, int out_size, void* d_ws, size_t ws_size,
                              hipStream_t stream)
{
  const float* feat  = (const float*)d_in[0];
  const float* coord = (const float*)d_in[1];
  const float* cell  = (const float*)d_in[2];
  const float* W0    = (const float*)d_in[3];
  const float* b0    = (const float*)d_in[4];
  const float* W1    = (const float*)d_in[5];
  const float* b1    = (const float*)d_in[6];
  const float* W2    = (const float*)d_in[7];
  const float* b2    = (const float*)d_in[8];
  const float* W3    = (const float*)d_in[9];
  const float* b3    = (const float*)d_in[10];
  const float* W4    = (const float*)d_in[11];
  const float* b4    = (const float*)d_in[12];
  float* outp = (float*)d_out;

  // ws layout: P f32 [2*2304*256] = 4,718,592 B | Wt bf16 3*64K = 393,216 B
  //            | W4t f32 3*256 = 3,072 B
  float*          P    = (float*)d_ws;
  unsigned short* wtp  = (unsigned short*)((char*)d_ws + 4718592);
  float*          w4tp = (float*)((char*)d_ws + 4718592 + 393216);

  hipLaunchKernelGGL(liif_precompute, dim3(2*(NPOS/4)), dim3(256), 0, stream,
                     feat, W0, b0, P);
  hipLaunchKernelGGL(liif_convert, dim3(769), dim3(256), 0, stream,
                     W1, W2, W3, W4, wtp, w4tp);
  hipLaunchKernelGGL(liif_main, dim3(4096), dim3(512), 0, stream,
                     coord, cell, P, W0, wtp, b1, b2, b3, b4, w4tp, outp);
}